// Round 13
// baseline (97.986 us; speedup 1.0000x reference)
//
#include <hip/hip_runtime.h>

#define NS   128          // samples
#define D_   8128         // feature dim (physical)
#define DP_  8192         // padded feature stride for bf16 copies (2^13)
#define P_   8128         // real pairs
#define PP   8192         // padded pairs
#define EPSV 1e-12f
#define NT   127          // fallback tiles
#define KS32 32           // gram k-slices (254 k-steps of 32: 8 per slice, last gets 6)
#define TNB  2048         // tile blocks (16 x 128)

typedef __attribute__((ext_vector_type(8))) short short8;
typedef __attribute__((ext_vector_type(4))) float f32x4;

// ---- bf16 helpers (top 16 bits of f32, RNE) ----
static __device__ __forceinline__ unsigned short f32_to_bf16_rne(float f) {
    unsigned int u = __float_as_uint(f);
    return (unsigned short)((u + 0x7fffu + ((u >> 16) & 1u)) >> 16);
}
static __device__ __forceinline__ float bf16_lo(unsigned int u) { return __uint_as_float(u << 16); }
static __device__ __forceinline__ float bf16_hi(unsigned int u) { return __uint_as_float(u & 0xffff0000u); }

// max((a-b)*inv, eps) for 4 packed bf16 values
static __device__ __forceinline__ f32x4 gen4(uint2 a, uint2 b, float inv) {
    f32x4 r;
    r.x = fmaxf((bf16_lo(a.x) - bf16_lo(b.x)) * inv, EPSV);
    r.y = fmaxf((bf16_hi(a.x) - bf16_hi(b.x)) * inv, EPSV);
    r.z = fmaxf((bf16_lo(a.y) - bf16_lo(b.y)) * inv, EPSV);
    r.w = fmaxf((bf16_hi(a.y) - bf16_hi(b.y)) * inv, EPSV);
    return r;
}

// ============ K1: fused fp32->bf16 convert + Gram MFMA partials + pad ============
// grid (KS32, 2), 256 thr. Slice sl covers k-steps [8sl, min(8sl+8,254)).
// Structure identical to round-8-proven gram_cvt (only the ks range differs).
__global__ void __launch_bounds__(256)
gram_cvt(const float* __restrict__ Sr, const float* __restrict__ Sf,
         unsigned short* __restrict__ Sr16, unsigned short* __restrict__ Sf16,
         float* __restrict__ Gpart) {
    int sl = blockIdx.x;
    int m  = blockIdx.y;
    const float* __restrict__ S = m ? Sf : Sr;
    unsigned short* __restrict__ S16 = m ? Sf16 : Sr16;
    float* __restrict__ out = Gpart + ((size_t)sl * 2 + m) * (NS * NS);

    __shared__ short St[128 * 40];   // [row][k], stride 40 bf16 (proven layout)

    int t = threadIdx.x;
    int w = t >> 6, l = t & 63;
    int lr = l & 15;
    int kf = (l >> 4) * 8;

    int ks0 = sl * 8;
    int ks1 = (ks0 + 8 < 254) ? ks0 + 8 : 254;

    f32x4 acc[2][8];
    #pragma unroll
    for (int fr = 0; fr < 2; ++fr)
        #pragma unroll
        for (int c = 0; c < 8; ++c) acc[fr][c] = (f32x4)0.f;

    for (int ks = ks0; ks < ks1; ++ks) {
        int k0 = ks * 32;
        #pragma unroll
        for (int g4 = 0; g4 < 4; ++g4) {
            int task = t + 256 * g4;       // 0..1023
            int row  = task >> 3;          // 0..127
            int g    = task & 7;           // cols 4g..4g+3
            float4 v = *(const float4*)(S + (size_t)row * D_ + k0 + 4 * g);
            ushort4 o;
            o.x = f32_to_bf16_rne(v.x);
            o.y = f32_to_bf16_rne(v.y);
            o.z = f32_to_bf16_rne(v.z);
            o.w = f32_to_bf16_rne(v.w);
            *(ushort4*)&St[row * 40 + 4 * g] = o;
            *(ushort4*)(S16 + (size_t)row * DP_ + k0 + 4 * g) = o;
        }
        __syncthreads();

        short8 a0 = *(const short8*)&St[(w * 32 + lr) * 40 + kf];
        short8 a1 = *(const short8*)&St[(w * 32 + 16 + lr) * 40 + kf];
        #pragma unroll
        for (int c = 0; c < 8; ++c) {
            short8 b = *(const short8*)&St[(c * 16 + lr) * 40 + kf];
            acc[0][c] = __builtin_amdgcn_mfma_f32_16x16x32_bf16(a0, b, acc[0][c], 0, 0, 0);
            acc[1][c] = __builtin_amdgcn_mfma_f32_16x16x32_bf16(a1, b, acc[1][c], 0, 0, 0);
        }
        __syncthreads();
    }

    // pad columns once (last slice pads its own matrix)
    if (sl == KS32 - 1) {
        #pragma unroll
        for (int g = 0; g < 4; ++g) {
            int idx = t + 256 * g;          // 0..1023 uint4 (128 rows x 8)
            int row = idx >> 3, c4 = idx & 7;
            uint4 z; z.x = 0u; z.y = 0u; z.z = 0u; z.w = 0u;
            *(uint4*)(S16 + (size_t)row * DP_ + D_ + 8 * c4) = z;
        }
    }

    // C/D: col = lane&15, row = (lane>>4)*4 + reg (G symmetric -> transpose-safe)
    #pragma unroll
    for (int fr = 0; fr < 2; ++fr) {
        int rbase = w * 32 + fr * 16 + (l >> 4) * 4;
        #pragma unroll
        for (int c = 0; c < 8; ++c) {
            int col = c * 16 + lr;
            #pragma unroll
            for (int r = 0; r < 4; ++r)
                out[(rbase + r) * NS + col] = acc[fr][c][r];
        }
    }
}

// ============ K2: pair metadata + inverse norms (sums KS32 slices) + counter reset ==
__global__ void norm_finish(const float* __restrict__ Gpart,
                            float* __restrict__ inv_nr, float* __restrict__ inv_nf,
                            int* __restrict__ opi, int* __restrict__ opj,
                            unsigned int* __restrict__ dcount) {
    int p = blockIdx.x * 256 + threadIdx.x;
    if (p == 0) *dcount = 0u;            // reset completion counter for K3
    if (p >= PP) return;
    if (p >= P_) {
        inv_nr[p] = 0.f;
        inv_nf[p] = 0.f;
        opi[p] = 0;
        opj[p] = 0;
        return;
    }
    int i = (int)((1.0f + sqrtf(8.0f * (float)p + 1.0f)) * 0.5f);
    while (i * (i - 1) / 2 > p) --i;
    while ((i + 1) * i / 2 <= p) ++i;
    int j = p - i * (i - 1) / 2;

    float rii = 0.f, rjj = 0.f, rij = 0.f;
    float fii = 0.f, fjj = 0.f, fij = 0.f;
    #pragma unroll 4
    for (int s = 0; s < KS32; ++s) {
        const float* g0 = Gpart + ((size_t)s * 2 + 0) * (NS * NS);
        const float* g1 = Gpart + ((size_t)s * 2 + 1) * (NS * NS);
        rii += g0[i * NS + i]; rjj += g0[j * NS + j]; rij += g0[i * NS + j];
        fii += g1[i * NS + i]; fjj += g1[j * NS + j]; fij += g1[i * NS + j];
    }
    inv_nr[p] = rsqrtf(fmaxf(rii + rjj - 2.f * rij, 1e-30f));
    inv_nf[p] = rsqrtf(fmaxf(fii + fjj - 2.f * fij, 1e-30f));
    opi[p] = i * DP_;
    opj[p] = j * DP_;
}

// ============ K3: tile10 (round-12-proven compute) + last-block final reduce ============
__global__ void __launch_bounds__(256, 6)
tile11_kernel(const unsigned short* __restrict__ Sr16, const unsigned short* __restrict__ Sf16,
              const float* __restrict__ inv_nr, const float* __restrict__ inv_nf,
              const int* __restrict__ opi, const int* __restrict__ opj,
              float* __restrict__ partials, unsigned int* __restrict__ dcount,
              float* __restrict__ out) {
    __shared__ unsigned short Sfl[128 * 64];   // [row][q-slot swizzled], 16 KB
    __shared__ float wsum[4];
    __shared__ float wsum2[4];
    __shared__ int lastFlag;

    int t  = threadIdx.x;
    int q0 = blockIdx.y * 64;
    int pg = t & 15;
    int qg = t >> 4;

    // ---- cache Sf[:, q0:q0+64] with (row&15) slot swizzle (8B granules)
    #pragma unroll
    for (int s = 0; s < 8; ++s) {
        int task = t + 256 * s;          // 0..2047 = 128 rows x 16 slots
        int row = task >> 4, slot = task & 15;
        uint2 v = *(const uint2*)(Sf16 + (size_t)row * DP_ + q0 + 4 * slot);
        *(uint2*)&Sfl[row * 64 + 4 * (slot ^ (row & 15))] = v;
    }

    // ---- q-side metadata (fixed per block): q = q0 + 4qg .. +3
    int q4 = q0 + 4 * qg;
    int4   oiq   = *(const int4*)&opi[q4];
    int4   ojq   = *(const int4*)&opj[q4];
    float4 invr4 = *(const float4*)&inv_nr[q4];
    __syncthreads();                      // the only barrier in the main path

    float acc = 0.f;
    for (int step = 0; step < 8; ++step) {
        int pb = ((blockIdx.x * 8 + step) << 6) + 4 * pg;   // this thread's 4 p's

        int4   pio   = *(const int4*)&opi[pb];
        int4   pjo   = *(const int4*)&opj[pb];
        float4 invf4 = *(const float4*)&inv_nf[pb];

        uint2 ru0 = *(const uint2*)(Sr16 + oiq.x + pb);
        uint2 rv0 = *(const uint2*)(Sr16 + ojq.x + pb);
        uint2 ru1 = *(const uint2*)(Sr16 + oiq.y + pb);
        uint2 rv1 = *(const uint2*)(Sr16 + ojq.y + pb);
        uint2 ru2 = *(const uint2*)(Sr16 + oiq.z + pb);
        uint2 rv2 = *(const uint2*)(Sr16 + ojq.z + pb);
        uint2 ru3 = *(const uint2*)(Sr16 + oiq.w + pb);
        uint2 rv3 = *(const uint2*)(Sr16 + ojq.w + pb);

        int ii0 = pio.x >> 13, jj0 = pjo.x >> 13;
        int ii1 = pio.y >> 13, jj1 = pjo.y >> 13;
        int ii2 = pio.z >> 13, jj2 = pjo.z >> 13;
        int ii3 = pio.w >> 13, jj3 = pjo.w >> 13;
        uint2 fu0 = *(const uint2*)&Sfl[ii0 * 64 + 4 * (qg ^ (ii0 & 15))];
        uint2 fv0 = *(const uint2*)&Sfl[jj0 * 64 + 4 * (qg ^ (jj0 & 15))];
        uint2 fu1 = *(const uint2*)&Sfl[ii1 * 64 + 4 * (qg ^ (ii1 & 15))];
        uint2 fv1 = *(const uint2*)&Sfl[jj1 * 64 + 4 * (qg ^ (jj1 & 15))];
        uint2 fu2 = *(const uint2*)&Sfl[ii2 * 64 + 4 * (qg ^ (ii2 & 15))];
        uint2 fv2 = *(const uint2*)&Sfl[jj2 * 64 + 4 * (qg ^ (jj2 & 15))];
        uint2 fu3 = *(const uint2*)&Sfl[ii3 * 64 + 4 * (qg ^ (ii3 & 15))];
        uint2 fv3 = *(const uint2*)&Sfl[jj3 * 64 + 4 * (qg ^ (jj3 & 15))];

        f32x4 R0 = gen4(ru0, rv0, invr4.x);   // R[q=0][p=0..3]
        f32x4 R1 = gen4(ru1, rv1, invr4.y);
        f32x4 R2 = gen4(ru2, rv2, invr4.z);
        f32x4 R3 = gen4(ru3, rv3, invr4.w);
        f32x4 F0 = gen4(fu0, fv0, invf4.x);   // F[p=0][q=0..3]
        f32x4 F1 = gen4(fu1, fv1, invf4.y);
        f32x4 F2 = gen4(fu2, fv2, invf4.z);
        f32x4 F3 = gen4(fu3, fv3, invf4.w);

        acc += F0.x * R0.x + F0.y * R1.x + F0.z * R2.x + F0.w * R3.x;
        acc += F1.x * R0.y + F1.y * R1.y + F1.z * R2.y + F1.w * R3.y;
        acc += F2.x * R0.z + F2.y * R1.z + F2.z * R2.z + F2.w * R3.z;
        acc += F3.x * R0.w + F3.y * R1.w + F3.z * R2.w + F3.w * R3.w;
    }

    // ---- per-block reduction
    #pragma unroll
    for (int off = 32; off > 0; off >>= 1) acc += __shfl_down(acc, off, 64);
    if ((t & 63) == 0) wsum[t >> 6] = acc;
    __syncthreads();

    // ---- publish partial; last block to finish does the final deterministic sum
    if (t == 0) {
        float tot = wsum[0] + wsum[1] + wsum[2] + wsum[3];
        partials[blockIdx.y * 16 + blockIdx.x] = tot;
        __threadfence();                              // make partial device-visible
        unsigned int prev = atomicAdd(dcount, 1u);
        lastFlag = (prev == TNB - 1) ? 1 : 0;
    }
    __syncthreads();
    if (lastFlag) {
        __threadfence();                              // acquire: see all partials
        float s = 0.f;
        #pragma unroll
        for (int k = 0; k < TNB / 256; ++k)           // fixed order -> deterministic
            s += partials[t + 256 * k];
        #pragma unroll
        for (int off = 32; off > 0; off >>= 1) s += __shfl_down(s, off, 64);
        if ((t & 63) == 0) wsum2[t >> 6] = s;
        __syncthreads();
        if (t == 0) out[0] = wsum2[0] + wsum2[1] + wsum2[2] + wsum2[3];
    }
}

// ============ fallback norms + fp32 tile + reduce (proven round-1/3 path) ============
__global__ void norms_kernel(const float* __restrict__ Sr, const float* __restrict__ Sf,
                             float* __restrict__ inv_nr, float* __restrict__ inv_nf,
                             int* __restrict__ opi, int* __restrict__ opj) {
    int p = blockIdx.x;
    int i = (int)((1.0f + sqrtf(8.0f * (float)p + 1.0f)) * 0.5f);
    while (i * (i - 1) / 2 > p) --i;
    while ((i + 1) * i / 2 <= p) ++i;
    int j = p - i * (i - 1) / 2;

    const float4* ri = (const float4*)(Sr + (size_t)i * D_);
    const float4* rj = (const float4*)(Sr + (size_t)j * D_);
    const float4* fi = (const float4*)(Sf + (size_t)i * D_);
    const float4* fj = (const float4*)(Sf + (size_t)j * D_);

    float sr = 0.f, sf = 0.f;
    for (int d = threadIdx.x; d < D_ / 4; d += 256) {
        float4 a = ri[d], b = rj[d];
        float dx = a.x - b.x, dy = a.y - b.y, dz = a.z - b.z, dw = a.w - b.w;
        sr += dx * dx + dy * dy + dz * dz + dw * dw;
        float4 c2 = fi[d], e = fj[d];
        dx = c2.x - e.x; dy = c2.y - e.y; dz = c2.z - e.z; dw = c2.w - e.w;
        sf += dx * dx + dy * dy + dz * dz + dw * dw;
    }
    #pragma unroll
    for (int off = 32; off > 0; off >>= 1) {
        sr += __shfl_down(sr, off, 64);
        sf += __shfl_down(sf, off, 64);
    }
    __shared__ float wr[4], wf[4];
    int wave = threadIdx.x >> 6;
    if ((threadIdx.x & 63) == 0) { wr[wave] = sr; wf[wave] = sf; }
    __syncthreads();
    if (threadIdx.x == 0) {
        inv_nr[p] = 1.0f / sqrtf(wr[0] + wr[1] + wr[2] + wr[3]);
        inv_nf[p] = 1.0f / sqrtf(wf[0] + wf[1] + wf[2] + wf[3]);
        opi[p] = i * D_;
        opj[p] = j * D_;
    }
}

__global__ void __launch_bounds__(256, 6)
tile3_kernel(const float* __restrict__ Sr, const float* __restrict__ Sf,
             const float* __restrict__ inv_nr, const float* __restrict__ inv_nf,
             const int* __restrict__ opi, const int* __restrict__ opj,
             float* __restrict__ partials) {
    __shared__ float Rt[64][65];
    __shared__ int   sIp[64], sJp[64];
    __shared__ float sInvF[64];
    __shared__ float wsum[4];

    int t  = threadIdx.x;
    int p0 = blockIdx.x * 64, q0 = blockIdx.y * 64;

    if (t < 64) {
        int p = p0 + t;
        sIp[t]   = opi[p];
        sJp[t]   = opj[p];
        sInvF[t] = inv_nf[p];
    }
    {
        int c  = t & 15;
        int qr = t >> 4;
        #pragma unroll
        for (int pass = 0; pass < 4; ++pass) {
            int qq = qr + 16 * pass;
            int q  = q0 + qq;
            int oi = opi[q], oj = opj[q];
            float invr = inv_nr[q];
            const float4 a = *(const float4*)(Sr + oi + p0 + 4 * c);
            const float4 b = *(const float4*)(Sr + oj + p0 + 4 * c);
            Rt[4 * c + 0][qq] = fmaxf((a.x - b.x) * invr, EPSV);
            Rt[4 * c + 1][qq] = fmaxf((a.y - b.y) * invr, EPSV);
            Rt[4 * c + 2][qq] = fmaxf((a.z - b.z) * invr, EPSV);
            Rt[4 * c + 3][qq] = fmaxf((a.w - b.w) * invr, EPSV);
        }
    }
    __syncthreads();

    int qg = t & 15;
    int pg = t >> 4;
    float ax = 0.f, ay = 0.f, az = 0.f, aw = 0.f;
    #pragma unroll
    for (int pp = 0; pp < 4; ++pp) {
        int prow = pg + 16 * pp;
        int oi = sIp[prow], oj = sJp[prow];
        float invf = sInvF[prow];
        const float4 fa = *(const float4*)(Sf + oi + q0 + 4 * qg);
        const float4 fb = *(const float4*)(Sf + oj + q0 + 4 * qg);
        const float4 r  = *(const float4*)&Rt[prow][4 * qg];
        ax += fmaxf((fa.x - fb.x) * invf, EPSV) * r.x;
        ay += fmaxf((fa.y - fb.y) * invf, EPSV) * r.y;
        az += fmaxf((fa.z - fb.z) * invf, EPSV) * r.z;
        aw += fmaxf((fa.w - fb.w) * invf, EPSV) * r.w;
    }
    float acc = (ax + ay) + (az + aw);

    #pragma unroll
    for (int off = 32; off > 0; off >>= 1) acc += __shfl_down(acc, off, 64);
    int w = t >> 6;
    if ((t & 63) == 0) wsum[w] = acc;
    __syncthreads();
    if (t == 0) partials[blockIdx.y * NT + blockIdx.x] = wsum[0] + wsum[1] + wsum[2] + wsum[3];
}

__global__ void reduce_kernel(const float* __restrict__ partials, int n, float* __restrict__ out) {
    float s = 0.f;
    for (int idx = threadIdx.x; idx < n; idx += 1024) s += partials[idx];
    #pragma unroll
    for (int off = 32; off > 0; off >>= 1) s += __shfl_down(s, off, 64);
    __shared__ float wbuf[16];
    int wave = threadIdx.x >> 6;
    if ((threadIdx.x & 63) == 0) wbuf[wave] = s;
    __syncthreads();
    if (threadIdx.x == 0) {
        float tot = 0.f;
        #pragma unroll
        for (int k = 0; k < 16; ++k) tot += wbuf[k];
        out[0] = tot;
    }
}

extern "C" void kernel_launch(void* const* d_in, const int* in_sizes, int n_in,
                              void* d_out, int out_size, void* d_ws, size_t ws_size,
                              hipStream_t stream) {
    const float* Sr = (const float*)d_in[0];
    const float* Sf = (const float*)d_in[1];
    float* out = (float*)d_out;

    // ws layout (all sub-buffer sizes multiples of 16 B)
    char* w = (char*)d_ws;
    unsigned short* Sr16 = (unsigned short*)w;   w += (size_t)NS * DP_ * 2;             // 2.10 MB
    unsigned short* Sf16 = (unsigned short*)w;   w += (size_t)NS * DP_ * 2;             // 2.10 MB
    float* inv_nr = (float*)w;                   w += (size_t)PP * 4;
    float* inv_nf = (float*)w;                   w += (size_t)PP * 4;
    int*   opi    = (int*)w;                     w += (size_t)PP * 4;
    int*   opj    = (int*)w;                     w += (size_t)PP * 4;
    float* tpart  = (float*)w;                   w += (size_t)16384 * 4;                // >= max grid
    float* Gpart  = (float*)w;                   w += (size_t)KS32 * 2 * NS * NS * 4;   // 4.2 MB
    unsigned int* dcount = (unsigned int*)w;     w += 16;
    size_t need = (size_t)(w - (char*)d_ws);

    if (ws_size >= need) {
        dim3 gg(KS32, 2);
        gram_cvt<<<gg, 256, 0, stream>>>(Sr, Sf, Sr16, Sf16, Gpart);
        norm_finish<<<32, 256, 0, stream>>>(Gpart, inv_nr, inv_nf, opi, opj, dcount);
        dim3 grid(16, 128);
        tile11_kernel<<<grid, 256, 0, stream>>>(Sr16, Sf16, inv_nr, inv_nf, opi, opj,
                                                tpart, dcount, out);
    } else {
        norms_kernel<<<P_, 256, 0, stream>>>(Sr, Sf, inv_nr, inv_nf, opi, opj);
        dim3 grid(NT, NT);
        tile3_kernel<<<grid, 256, 0, stream>>>(Sr, Sf, inv_nr, inv_nf, opi, opj, tpart);
        reduce_kernel<<<1, 1024, 0, stream>>>(tpart, NT * NT, out);
    }
}

// Round 14
// 67.949 us; speedup vs baseline: 1.4421x; 1.4421x over previous
//
#include <hip/hip_runtime.h>

#define NS   128          // samples
#define D_   8128         // feature dim (physical)
#define DP_  8192         // padded feature stride for bf16 copies (2^13)
#define P_   8128         // real pairs
#define PP   8192         // padded pairs
#define EPSV 1e-12f
#define NT   127          // fallback tiles
#define KS8  8            // gram k-slices

typedef __attribute__((ext_vector_type(8))) short short8;
typedef __attribute__((ext_vector_type(4))) float f32x4;

// ---- bf16 helpers (top 16 bits of f32, RNE) ----
static __device__ __forceinline__ unsigned short f32_to_bf16_rne(float f) {
    unsigned int u = __float_as_uint(f);
    return (unsigned short)((u + 0x7fffu + ((u >> 16) & 1u)) >> 16);
}
static __device__ __forceinline__ unsigned int pack2_bf16(float a, float b) {
    return (unsigned int)f32_to_bf16_rne(a) | ((unsigned int)f32_to_bf16_rne(b) << 16);
}
static __device__ __forceinline__ float bf16_lo(unsigned int u) { return __uint_as_float(u << 16); }
static __device__ __forceinline__ float bf16_hi(unsigned int u) { return __uint_as_float(u & 0xffff0000u); }

// max((a-b)*inv, eps) for 4 packed bf16 values
static __device__ __forceinline__ f32x4 gen4(uint2 a, uint2 b, float inv) {
    f32x4 r;
    r.x = fmaxf((bf16_lo(a.x) - bf16_lo(b.x)) * inv, EPSV);
    r.y = fmaxf((bf16_hi(a.x) - bf16_hi(b.x)) * inv, EPSV);
    r.z = fmaxf((bf16_lo(a.y) - bf16_lo(b.y)) * inv, EPSV);
    r.w = fmaxf((bf16_hi(a.y) - bf16_hi(b.y)) * inv, EPSV);
    return r;
}

// ============ K1: fp32 -> bf16 copies with padded stride, pad cols zeroed ============
__global__ void cvt_pad(const float* __restrict__ Sr, const float* __restrict__ Sf,
                        unsigned short* __restrict__ Sr16, unsigned short* __restrict__ Sf16) {
    int idx = blockIdx.x * 256 + threadIdx.x;
    int m   = idx >> 17;
    int rem = idx & 131071;
    int row = rem >> 10;
    int c8  = rem & 1023;
    const float* __restrict__ S = m ? Sf : Sr;
    unsigned short* __restrict__ Dst = m ? Sf16 : Sr16;
    uint4 o;
    if (c8 < 1016) {
        const float* src = S + (size_t)row * D_ + 8 * c8;
        float4 v0 = *(const float4*)src;
        float4 v1 = *(const float4*)(src + 4);
        o.x = pack2_bf16(v0.x, v0.y);
        o.y = pack2_bf16(v0.z, v0.w);
        o.z = pack2_bf16(v1.x, v1.y);
        o.w = pack2_bf16(v1.z, v1.w);
    } else {
        o.x = 0u; o.y = 0u; o.z = 0u; o.w = 0u;
    }
    *(uint4*)(Dst + (size_t)row * DP_ + 8 * c8) = o;
}

// ============ K2: Gram direct — one wave per 16x16 G-tile per k-slice ============
__global__ void __launch_bounds__(64)
gram_direct(const unsigned short* __restrict__ Sr16, const unsigned short* __restrict__ Sf16,
            float* __restrict__ Gpart8) {
    int tile = blockIdx.x;
    int I = tile >> 3, J = tile & 7;
    int m = blockIdx.y;
    int s = blockIdx.z;
    const unsigned short* __restrict__ S = m ? Sf16 : Sr16;
    float* __restrict__ out = Gpart8 + ((size_t)s * 2 + m) * (NS * NS);

    int l  = threadIdx.x;
    int lr = l & 15;
    int kf = (l >> 4) * 8;

    const unsigned short* pa = S + (size_t)(I * 16 + lr) * DP_ + kf;
    const unsigned short* pb = S + (size_t)(J * 16 + lr) * DP_ + kf;

    f32x4 acc = (f32x4)0.f;
    int ks0 = s * 32;
    int ks1 = (ks0 + 32 < 254) ? ks0 + 32 : 254;
    #pragma unroll 4
    for (int ks = ks0; ks < ks1; ++ks) {
        short8 a = *(const short8*)(pa + ks * 32);
        short8 b = *(const short8*)(pb + ks * 32);
        acc = __builtin_amdgcn_mfma_f32_16x16x32_bf16(a, b, acc, 0, 0, 0);
    }
    int rbase = I * 16 + (l >> 4) * 4;
    int col   = J * 16 + lr;
    #pragma unroll
    for (int r = 0; r < 4; ++r)
        out[(rbase + r) * NS + col] = acc[r];
}

// ============ K3: pair metadata + inverse norms ============
__global__ void norm_finish(const float* __restrict__ Gpart8,
                            float* __restrict__ inv_nr, float* __restrict__ inv_nf,
                            int* __restrict__ opi, int* __restrict__ opj) {
    int p = blockIdx.x * 256 + threadIdx.x;
    if (p >= PP) return;
    if (p >= P_) {
        inv_nr[p] = 0.f;
        inv_nf[p] = 0.f;
        opi[p] = 0;
        opj[p] = 0;
        return;
    }
    int i = (int)((1.0f + sqrtf(8.0f * (float)p + 1.0f)) * 0.5f);
    while (i * (i - 1) / 2 > p) --i;
    while ((i + 1) * i / 2 <= p) ++i;
    int j = p - i * (i - 1) / 2;

    float rii = 0.f, rjj = 0.f, rij = 0.f;
    float fii = 0.f, fjj = 0.f, fij = 0.f;
    #pragma unroll
    for (int s = 0; s < KS8; ++s) {
        const float* g0 = Gpart8 + ((size_t)s * 2 + 0) * (NS * NS);
        const float* g1 = Gpart8 + ((size_t)s * 2 + 1) * (NS * NS);
        rii += g0[i * NS + i]; rjj += g0[j * NS + j]; rij += g0[i * NS + j];
        fii += g1[i * NS + i]; fjj += g1[j * NS + j]; fij += g1[i * NS + j];
    }
    inv_nr[p] = rsqrtf(fmaxf(rii + rjj - 2.f * rij, 1e-30f));
    inv_nf[p] = rsqrtf(fmaxf(fii + fjj - 2.f * fij, 1e-30f));
    opi[p] = i * DP_;
    opj[p] = j * DP_;
}

// ============ K4: tile12 — tile10 + hoisted R bases + unroll-4 ILP ============
// grid (16 p-strips, 128 q-tiles), 256 thr. No fences, no atomics.
__global__ void __launch_bounds__(256, 6)
tile12_kernel(const unsigned short* __restrict__ Sr16, const unsigned short* __restrict__ Sf16,
              const float* __restrict__ inv_nr, const float* __restrict__ inv_nf,
              const int* __restrict__ opi, const int* __restrict__ opj,
              float* __restrict__ partials) {
    __shared__ unsigned short Sfl[128 * 64];   // [row][q-slot swizzled], 16 KB
    __shared__ float wsum[4];

    int t  = threadIdx.x;
    int q0 = blockIdx.y * 64;
    int pg = t & 15;
    int qg = t >> 4;

    // ---- cache Sf[:, q0:q0+64] with (row&15) slot swizzle (8B granules)
    #pragma unroll
    for (int s = 0; s < 8; ++s) {
        int task = t + 256 * s;          // 0..2047 = 128 rows x 16 slots
        int row = task >> 4, slot = task & 15;
        uint2 v = *(const uint2*)(Sf16 + (size_t)row * DP_ + q0 + 4 * slot);
        *(uint2*)&Sfl[row * 64 + 4 * (slot ^ (row & 15))] = v;
    }

    // ---- q-side metadata (fixed per block): q = q0 + 4qg .. +3
    int q4 = q0 + 4 * qg;
    int4   oiq   = *(const int4*)&opi[q4];
    int4   ojq   = *(const int4*)&opj[q4];
    float4 invr4 = *(const float4*)&inv_nr[q4];
    __syncthreads();                      // the only barrier

    // ---- hoisted per-thread R row pointers (block-invariant) offset by thread p-base
    int pbBase = (blockIdx.x << 9) + 4 * pg;    // blockIdx.x*8 steps * 64 + 4*pg
    const unsigned short* pru0 = Sr16 + oiq.x + pbBase;
    const unsigned short* prv0 = Sr16 + ojq.x + pbBase;
    const unsigned short* pru1 = Sr16 + oiq.y + pbBase;
    const unsigned short* prv1 = Sr16 + ojq.y + pbBase;
    const unsigned short* pru2 = Sr16 + oiq.z + pbBase;
    const unsigned short* prv2 = Sr16 + ojq.z + pbBase;
    const unsigned short* pru3 = Sr16 + oiq.w + pbBase;
    const unsigned short* prv3 = Sr16 + ojq.w + pbBase;
    const int*   ppi = opi    + pbBase;
    const int*   ppj = opj    + pbBase;
    const float* pnf = inv_nf + pbBase;

    float acc = 0.f;
    #pragma unroll 4
    for (int step = 0; step < 8; ++step) {
        const int so = step * 64;                 // element offset -> imm-foldable

        int4   pio   = *(const int4*)(ppi + so);
        int4   pjo   = *(const int4*)(ppj + so);
        float4 invf4 = *(const float4*)(pnf + so);

        uint2 ru0 = *(const uint2*)(pru0 + so);
        uint2 rv0 = *(const uint2*)(prv0 + so);
        uint2 ru1 = *(const uint2*)(pru1 + so);
        uint2 rv1 = *(const uint2*)(prv1 + so);
        uint2 ru2 = *(const uint2*)(pru2 + so);
        uint2 rv2 = *(const uint2*)(prv2 + so);
        uint2 ru3 = *(const uint2*)(pru3 + so);
        uint2 rv3 = *(const uint2*)(prv3 + so);

        int ii0 = pio.x >> 13, jj0 = pjo.x >> 13;
        int ii1 = pio.y >> 13, jj1 = pjo.y >> 13;
        int ii2 = pio.z >> 13, jj2 = pjo.z >> 13;
        int ii3 = pio.w >> 13, jj3 = pjo.w >> 13;
        uint2 fu0 = *(const uint2*)&Sfl[ii0 * 64 + 4 * (qg ^ (ii0 & 15))];
        uint2 fv0 = *(const uint2*)&Sfl[jj0 * 64 + 4 * (qg ^ (jj0 & 15))];
        uint2 fu1 = *(const uint2*)&Sfl[ii1 * 64 + 4 * (qg ^ (ii1 & 15))];
        uint2 fv1 = *(const uint2*)&Sfl[jj1 * 64 + 4 * (qg ^ (jj1 & 15))];
        uint2 fu2 = *(const uint2*)&Sfl[ii2 * 64 + 4 * (qg ^ (ii2 & 15))];
        uint2 fv2 = *(const uint2*)&Sfl[jj2 * 64 + 4 * (qg ^ (jj2 & 15))];
        uint2 fu3 = *(const uint2*)&Sfl[ii3 * 64 + 4 * (qg ^ (ii3 & 15))];
        uint2 fv3 = *(const uint2*)&Sfl[jj3 * 64 + 4 * (qg ^ (jj3 & 15))];

        f32x4 R0 = gen4(ru0, rv0, invr4.x);   // R[q=0][p=0..3]
        f32x4 R1 = gen4(ru1, rv1, invr4.y);
        f32x4 R2 = gen4(ru2, rv2, invr4.z);
        f32x4 R3 = gen4(ru3, rv3, invr4.w);
        f32x4 F0 = gen4(fu0, fv0, invf4.x);   // F[p=0][q=0..3]
        f32x4 F1 = gen4(fu1, fv1, invf4.y);
        f32x4 F2 = gen4(fu2, fv2, invf4.z);
        f32x4 F3 = gen4(fu3, fv3, invf4.w);

        acc += F0.x * R0.x + F0.y * R1.x + F0.z * R2.x + F0.w * R3.x;
        acc += F1.x * R0.y + F1.y * R1.y + F1.z * R2.y + F1.w * R3.y;
        acc += F2.x * R0.z + F2.y * R1.z + F2.z * R2.z + F2.w * R3.z;
        acc += F3.x * R0.w + F3.y * R1.w + F3.z * R2.w + F3.w * R3.w;
    }

    // ---- one reduction per block
    #pragma unroll
    for (int off = 32; off > 0; off >>= 1) acc += __shfl_down(acc, off, 64);
    if ((t & 63) == 0) wsum[t >> 6] = acc;
    __syncthreads();
    if (t == 0) partials[blockIdx.y * 16 + blockIdx.x] = wsum[0] + wsum[1] + wsum[2] + wsum[3];
}

// ============ fallback norms + fp32 tile (proven round-1/3 path, D_ strides) ============
__global__ void norms_kernel(const float* __restrict__ Sr, const float* __restrict__ Sf,
                             float* __restrict__ inv_nr, float* __restrict__ inv_nf,
                             int* __restrict__ opi, int* __restrict__ opj) {
    int p = blockIdx.x;
    int i = (int)((1.0f + sqrtf(8.0f * (float)p + 1.0f)) * 0.5f);
    while (i * (i - 1) / 2 > p) --i;
    while ((i + 1) * i / 2 <= p) ++i;
    int j = p - i * (i - 1) / 2;

    const float4* ri = (const float4*)(Sr + (size_t)i * D_);
    const float4* rj = (const float4*)(Sr + (size_t)j * D_);
    const float4* fi = (const float4*)(Sf + (size_t)i * D_);
    const float4* fj = (const float4*)(Sf + (size_t)j * D_);

    float sr = 0.f, sf = 0.f;
    for (int d = threadIdx.x; d < D_ / 4; d += 256) {
        float4 a = ri[d], b = rj[d];
        float dx = a.x - b.x, dy = a.y - b.y, dz = a.z - b.z, dw = a.w - b.w;
        sr += dx * dx + dy * dy + dz * dz + dw * dw;
        float4 c2 = fi[d], e = fj[d];
        dx = c2.x - e.x; dy = c2.y - e.y; dz = c2.z - e.z; dw = c2.w - e.w;
        sf += dx * dx + dy * dy + dz * dz + dw * dw;
    }
    #pragma unroll
    for (int off = 32; off > 0; off >>= 1) {
        sr += __shfl_down(sr, off, 64);
        sf += __shfl_down(sf, off, 64);
    }
    __shared__ float wr[4], wf[4];
    int wave = threadIdx.x >> 6;
    if ((threadIdx.x & 63) == 0) { wr[wave] = sr; wf[wave] = sf; }
    __syncthreads();
    if (threadIdx.x == 0) {
        inv_nr[p] = 1.0f / sqrtf(wr[0] + wr[1] + wr[2] + wr[3]);
        inv_nf[p] = 1.0f / sqrtf(wf[0] + wf[1] + wf[2] + wf[3]);
        opi[p] = i * D_;
        opj[p] = j * D_;
    }
}

__global__ void __launch_bounds__(256, 6)
tile3_kernel(const float* __restrict__ Sr, const float* __restrict__ Sf,
             const float* __restrict__ inv_nr, const float* __restrict__ inv_nf,
             const int* __restrict__ opi, const int* __restrict__ opj,
             float* __restrict__ partials) {
    __shared__ float Rt[64][65];
    __shared__ int   sIp[64], sJp[64];
    __shared__ float sInvF[64];
    __shared__ float wsum[4];

    int t  = threadIdx.x;
    int p0 = blockIdx.x * 64, q0 = blockIdx.y * 64;

    if (t < 64) {
        int p = p0 + t;
        sIp[t]   = opi[p];
        sJp[t]   = opj[p];
        sInvF[t] = inv_nf[p];
    }
    {
        int c  = t & 15;
        int qr = t >> 4;
        #pragma unroll
        for (int pass = 0; pass < 4; ++pass) {
            int qq = qr + 16 * pass;
            int q  = q0 + qq;
            int oi = opi[q], oj = opj[q];
            float invr = inv_nr[q];
            const float4 a = *(const float4*)(Sr + oi + p0 + 4 * c);
            const float4 b = *(const float4*)(Sr + oj + p0 + 4 * c);
            Rt[4 * c + 0][qq] = fmaxf((a.x - b.x) * invr, EPSV);
            Rt[4 * c + 1][qq] = fmaxf((a.y - b.y) * invr, EPSV);
            Rt[4 * c + 2][qq] = fmaxf((a.z - b.z) * invr, EPSV);
            Rt[4 * c + 3][qq] = fmaxf((a.w - b.w) * invr, EPSV);
        }
    }
    __syncthreads();

    int qg = t & 15;
    int pg = t >> 4;
    float ax = 0.f, ay = 0.f, az = 0.f, aw = 0.f;
    #pragma unroll
    for (int pp = 0; pp < 4; ++pp) {
        int prow = pg + 16 * pp;
        int oi = sIp[prow], oj = sJp[prow];
        float invf = sInvF[prow];
        const float4 fa = *(const float4*)(Sf + oi + q0 + 4 * qg);
        const float4 fb = *(const float4*)(Sf + oj + q0 + 4 * qg);
        const float4 r  = *(const float4*)&Rt[prow][4 * qg];
        ax += fmaxf((fa.x - fb.x) * invf, EPSV) * r.x;
        ay += fmaxf((fa.y - fb.y) * invf, EPSV) * r.y;
        az += fmaxf((fa.z - fb.z) * invf, EPSV) * r.z;
        aw += fmaxf((fa.w - fb.w) * invf, EPSV) * r.w;
    }
    float acc = (ax + ay) + (az + aw);

    #pragma unroll
    for (int off = 32; off > 0; off >>= 1) acc += __shfl_down(acc, off, 64);
    int w = t >> 6;
    if ((t & 63) == 0) wsum[w] = acc;
    __syncthreads();
    if (t == 0) partials[blockIdx.y * NT + blockIdx.x] = wsum[0] + wsum[1] + wsum[2] + wsum[3];
}

// ============ K5: final deterministic reduce (1024 thr) ============
__global__ void reduce_kernel(const float* __restrict__ partials, int n, float* __restrict__ out) {
    float s = 0.f;
    for (int idx = threadIdx.x; idx < n; idx += 1024) s += partials[idx];
    #pragma unroll
    for (int off = 32; off > 0; off >>= 1) s += __shfl_down(s, off, 64);
    __shared__ float wbuf[16];
    int wave = threadIdx.x >> 6;
    if ((threadIdx.x & 63) == 0) wbuf[wave] = s;
    __syncthreads();
    if (threadIdx.x == 0) {
        float tot = 0.f;
        #pragma unroll
        for (int k = 0; k < 16; ++k) tot += wbuf[k];
        out[0] = tot;
    }
}

extern "C" void kernel_launch(void* const* d_in, const int* in_sizes, int n_in,
                              void* d_out, int out_size, void* d_ws, size_t ws_size,
                              hipStream_t stream) {
    const float* Sr = (const float*)d_in[0];
    const float* Sf = (const float*)d_in[1];
    float* out = (float*)d_out;

    // ws layout (all sub-buffer sizes multiples of 16 B)
    char* w = (char*)d_ws;
    unsigned short* Sr16 = (unsigned short*)w;   w += (size_t)NS * DP_ * 2;            // 2.10 MB
    unsigned short* Sf16 = (unsigned short*)w;   w += (size_t)NS * DP_ * 2;            // 2.10 MB
    float* inv_nr = (float*)w;                   w += (size_t)PP * 4;
    float* inv_nf = (float*)w;                   w += (size_t)PP * 4;
    int*   opi    = (int*)w;                     w += (size_t)PP * 4;
    int*   opj    = (int*)w;                     w += (size_t)PP * 4;
    float* tpart  = (float*)w;                   w += (size_t)16384 * 4;               // >= max grid
    float* Gpart8 = (float*)w;                   w += (size_t)KS8 * 2 * NS * NS * 4;   // 1.05 MB
    size_t need = (size_t)(w - (char*)d_ws);

    if (ws_size >= need) {
        cvt_pad<<<1024, 256, 0, stream>>>(Sr, Sf, Sr16, Sf16);
        dim3 gg(64, 2, KS8);
        gram_direct<<<gg, 64, 0, stream>>>(Sr16, Sf16, Gpart8);
        norm_finish<<<32, 256, 0, stream>>>(Gpart8, inv_nr, inv_nf, opi, opj);
        dim3 grid(16, 128);
        tile12_kernel<<<grid, 256, 0, stream>>>(Sr16, Sf16, inv_nr, inv_nf, opi, opj, tpart);
        reduce_kernel<<<1, 1024, 0, stream>>>(tpart, 2048, out);
    } else {
        norms_kernel<<<P_, 256, 0, stream>>>(Sr, Sf, inv_nr, inv_nf, opi, opj);
        dim3 grid(NT, NT);
        tile3_kernel<<<grid, 256, 0, stream>>>(Sr, Sf, inv_nr, inv_nf, opi, opj, tpart);
        reduce_kernel<<<1, 1024, 0, stream>>>(tpart, NT * NT, out);
    }
}

// Round 15
// 54.099 us; speedup vs baseline: 1.8112x; 1.2560x over previous
//
#include <hip/hip_runtime.h>

#define NS   128          // samples
#define D_   8128         // feature dim (physical)
#define DP_  8192         // padded feature stride for bf16 copies (2^13)
#define P_   8128         // real pairs
#define PP   8192         // padded pairs
#define EPSV 1e-12f
#define NT   127          // fallback tiles
#define KS8  8            // gram k-slices

typedef __attribute__((ext_vector_type(8))) short short8;
typedef __attribute__((ext_vector_type(4))) float f32x4;

// ---- bf16 helpers (top 16 bits of f32, RNE) ----
static __device__ __forceinline__ unsigned short f32_to_bf16_rne(float f) {
    unsigned int u = __float_as_uint(f);
    return (unsigned short)((u + 0x7fffu + ((u >> 16) & 1u)) >> 16);
}
static __device__ __forceinline__ unsigned int pack2_bf16(float a, float b) {
    return (unsigned int)f32_to_bf16_rne(a) | ((unsigned int)f32_to_bf16_rne(b) << 16);
}
static __device__ __forceinline__ float bf16_lo(unsigned int u) { return __uint_as_float(u << 16); }
static __device__ __forceinline__ float bf16_hi(unsigned int u) { return __uint_as_float(u & 0xffff0000u); }

// max((a-b)*inv, eps) for 4 packed bf16 values
static __device__ __forceinline__ f32x4 gen4(uint2 a, uint2 b, float inv) {
    f32x4 r;
    r.x = fmaxf((bf16_lo(a.x) - bf16_lo(b.x)) * inv, EPSV);
    r.y = fmaxf((bf16_hi(a.x) - bf16_hi(b.x)) * inv, EPSV);
    r.z = fmaxf((bf16_lo(a.y) - bf16_lo(b.y)) * inv, EPSV);
    r.w = fmaxf((bf16_hi(a.y) - bf16_hi(b.y)) * inv, EPSV);
    return r;
}

// ============ K1: fp32 -> bf16 copies with padded stride, pad cols zeroed ============
__global__ void cvt_pad(const float* __restrict__ Sr, const float* __restrict__ Sf,
                        unsigned short* __restrict__ Sr16, unsigned short* __restrict__ Sf16) {
    int idx = blockIdx.x * 256 + threadIdx.x;
    int m   = idx >> 17;
    int rem = idx & 131071;
    int row = rem >> 10;
    int c8  = rem & 1023;
    const float* __restrict__ S = m ? Sf : Sr;
    unsigned short* __restrict__ Dst = m ? Sf16 : Sr16;
    uint4 o;
    if (c8 < 1016) {
        const float* src = S + (size_t)row * D_ + 8 * c8;
        float4 v0 = *(const float4*)src;
        float4 v1 = *(const float4*)(src + 4);
        o.x = pack2_bf16(v0.x, v0.y);
        o.y = pack2_bf16(v0.z, v0.w);
        o.z = pack2_bf16(v1.x, v1.y);
        o.w = pack2_bf16(v1.z, v1.w);
    } else {
        o.x = 0u; o.y = 0u; o.z = 0u; o.w = 0u;
    }
    *(uint4*)(Dst + (size_t)row * DP_ + 8 * c8) = o;
}

// ============ K2: Gram direct — one wave per 16x16 G-tile per k-slice ============
__global__ void __launch_bounds__(64)
gram_direct(const unsigned short* __restrict__ Sr16, const unsigned short* __restrict__ Sf16,
            float* __restrict__ Gpart8) {
    int tile = blockIdx.x;
    int I = tile >> 3, J = tile & 7;
    int m = blockIdx.y;
    int s = blockIdx.z;
    const unsigned short* __restrict__ S = m ? Sf16 : Sr16;
    float* __restrict__ out = Gpart8 + ((size_t)s * 2 + m) * (NS * NS);

    int l  = threadIdx.x;
    int lr = l & 15;
    int kf = (l >> 4) * 8;

    const unsigned short* pa = S + (size_t)(I * 16 + lr) * DP_ + kf;
    const unsigned short* pb = S + (size_t)(J * 16 + lr) * DP_ + kf;

    f32x4 acc = (f32x4)0.f;
    int ks0 = s * 32;
    int ks1 = (ks0 + 32 < 254) ? ks0 + 32 : 254;
    #pragma unroll 4
    for (int ks = ks0; ks < ks1; ++ks) {
        short8 a = *(const short8*)(pa + ks * 32);
        short8 b = *(const short8*)(pb + ks * 32);
        acc = __builtin_amdgcn_mfma_f32_16x16x32_bf16(a, b, acc, 0, 0, 0);
    }
    int rbase = I * 16 + (l >> 4) * 4;
    int col   = J * 16 + lr;
    #pragma unroll
    for (int r = 0; r < 4; ++r)
        out[(rbase + r) * NS + col] = acc[r];
}

// ============ K3: pair metadata + inverse norms ============
__global__ void norm_finish(const float* __restrict__ Gpart8,
                            float* __restrict__ inv_nr, float* __restrict__ inv_nf,
                            int* __restrict__ opi, int* __restrict__ opj) {
    int p = blockIdx.x * 256 + threadIdx.x;
    if (p >= PP) return;
    if (p >= P_) {
        inv_nr[p] = 0.f;
        inv_nf[p] = 0.f;
        opi[p] = 0;
        opj[p] = 0;
        return;
    }
    int i = (int)((1.0f + sqrtf(8.0f * (float)p + 1.0f)) * 0.5f);
    while (i * (i - 1) / 2 > p) --i;
    while ((i + 1) * i / 2 <= p) ++i;
    int j = p - i * (i - 1) / 2;

    float rii = 0.f, rjj = 0.f, rij = 0.f;
    float fii = 0.f, fjj = 0.f, fij = 0.f;
    #pragma unroll
    for (int s = 0; s < KS8; ++s) {
        const float* g0 = Gpart8 + ((size_t)s * 2 + 0) * (NS * NS);
        const float* g1 = Gpart8 + ((size_t)s * 2 + 1) * (NS * NS);
        rii += g0[i * NS + i]; rjj += g0[j * NS + j]; rij += g0[i * NS + j];
        fii += g1[i * NS + i]; fjj += g1[j * NS + j]; fij += g1[i * NS + j];
    }
    inv_nr[p] = rsqrtf(fmaxf(rii + rjj - 2.f * rij, 1e-30f));
    inv_nf[p] = rsqrtf(fmaxf(fii + fjj - 2.f * fij, 1e-30f));
    opi[p] = i * DP_;
    opj[p] = j * DP_;
}

// ============ K4: tile13 — round-12-proven tile10 body, occupancy bound 6 -> 8 ============
// grid (16 p-strips, 128 q-tiles), 256 thr. VGPR ~40 <= 64 cap (no spill);
// LDS 16.9 KB x 8 blocks = 135 KB <= 160 KB. 32 waves/CU.
__global__ void __launch_bounds__(256, 8)
tile13_kernel(const unsigned short* __restrict__ Sr16, const unsigned short* __restrict__ Sf16,
              const float* __restrict__ inv_nr, const float* __restrict__ inv_nf,
              const int* __restrict__ opi, const int* __restrict__ opj,
              float* __restrict__ partials) {
    __shared__ unsigned short Sfl[128 * 64];   // [row][q-slot swizzled], 16 KB
    __shared__ float wsum[4];

    int t  = threadIdx.x;
    int q0 = blockIdx.y * 64;
    int pg = t & 15;
    int qg = t >> 4;

    // ---- cache Sf[:, q0:q0+64] with (row&15) slot swizzle (8B granules)
    #pragma unroll
    for (int s = 0; s < 8; ++s) {
        int task = t + 256 * s;          // 0..2047 = 128 rows x 16 slots
        int row = task >> 4, slot = task & 15;
        uint2 v = *(const uint2*)(Sf16 + (size_t)row * DP_ + q0 + 4 * slot);
        *(uint2*)&Sfl[row * 64 + 4 * (slot ^ (row & 15))] = v;
    }

    // ---- q-side metadata (fixed per block): q = q0 + 4qg .. +3
    int q4 = q0 + 4 * qg;
    int4   oiq   = *(const int4*)&opi[q4];
    int4   ojq   = *(const int4*)&opj[q4];
    float4 invr4 = *(const float4*)&inv_nr[q4];
    __syncthreads();                      // the only barrier

    float acc = 0.f;
    for (int step = 0; step < 8; ++step) {
        int pb = ((blockIdx.x * 8 + step) << 6) + 4 * pg;   // this thread's 4 p's

        // p-side metadata (coalesced int4/float4 across lanes 0..15)
        int4   pio   = *(const int4*)&opi[pb];
        int4   pjo   = *(const int4*)&opj[pb];
        float4 invf4 = *(const float4*)&inv_nf[pb];

        // R operands: 4 q-rows x 2, cols pb..pb+3 (lanes 0..15 -> 128B contiguous)
        uint2 ru0 = *(const uint2*)(Sr16 + oiq.x + pb);
        uint2 rv0 = *(const uint2*)(Sr16 + ojq.x + pb);
        uint2 ru1 = *(const uint2*)(Sr16 + oiq.y + pb);
        uint2 rv1 = *(const uint2*)(Sr16 + ojq.y + pb);
        uint2 ru2 = *(const uint2*)(Sr16 + oiq.z + pb);
        uint2 rv2 = *(const uint2*)(Sr16 + ojq.z + pb);
        uint2 ru3 = *(const uint2*)(Sr16 + oiq.w + pb);
        uint2 rv3 = *(const uint2*)(Sr16 + ojq.w + pb);

        // F operands from swizzled LDS: 4 p-rows x 2
        int ii0 = pio.x >> 13, jj0 = pjo.x >> 13;
        int ii1 = pio.y >> 13, jj1 = pjo.y >> 13;
        int ii2 = pio.z >> 13, jj2 = pjo.z >> 13;
        int ii3 = pio.w >> 13, jj3 = pjo.w >> 13;
        uint2 fu0 = *(const uint2*)&Sfl[ii0 * 64 + 4 * (qg ^ (ii0 & 15))];
        uint2 fv0 = *(const uint2*)&Sfl[jj0 * 64 + 4 * (qg ^ (jj0 & 15))];
        uint2 fu1 = *(const uint2*)&Sfl[ii1 * 64 + 4 * (qg ^ (ii1 & 15))];
        uint2 fv1 = *(const uint2*)&Sfl[jj1 * 64 + 4 * (qg ^ (jj1 & 15))];
        uint2 fu2 = *(const uint2*)&Sfl[ii2 * 64 + 4 * (qg ^ (ii2 & 15))];
        uint2 fv2 = *(const uint2*)&Sfl[jj2 * 64 + 4 * (qg ^ (jj2 & 15))];
        uint2 fu3 = *(const uint2*)&Sfl[ii3 * 64 + 4 * (qg ^ (ii3 & 15))];
        uint2 fv3 = *(const uint2*)&Sfl[jj3 * 64 + 4 * (qg ^ (jj3 & 15))];

        // generate values
        f32x4 R0 = gen4(ru0, rv0, invr4.x);   // R[q=0][p=0..3]
        f32x4 R1 = gen4(ru1, rv1, invr4.y);
        f32x4 R2 = gen4(ru2, rv2, invr4.z);
        f32x4 R3 = gen4(ru3, rv3, invr4.w);
        f32x4 F0 = gen4(fu0, fv0, invf4.x);   // F[p=0][q=0..3]
        f32x4 F1 = gen4(fu1, fv1, invf4.y);
        f32x4 F2 = gen4(fu2, fv2, invf4.z);
        f32x4 F3 = gen4(fu3, fv3, invf4.w);

        // acc += sum_{r,c} F[r][c] * R[c][r]
        acc += F0.x * R0.x + F0.y * R1.x + F0.z * R2.x + F0.w * R3.x;
        acc += F1.x * R0.y + F1.y * R1.y + F1.z * R2.y + F1.w * R3.y;
        acc += F2.x * R0.z + F2.y * R1.z + F2.z * R2.z + F2.w * R3.z;
        acc += F3.x * R0.w + F3.y * R1.w + F3.z * R2.w + F3.w * R3.w;
    }

    // ---- one reduction per block
    #pragma unroll
    for (int off = 32; off > 0; off >>= 1) acc += __shfl_down(acc, off, 64);
    if ((t & 63) == 0) wsum[t >> 6] = acc;
    __syncthreads();
    if (t == 0) partials[blockIdx.y * 16 + blockIdx.x] = wsum[0] + wsum[1] + wsum[2] + wsum[3];
}

// ============ fallback norms + fp32 tile (proven round-1/3 path, D_ strides) ============
__global__ void norms_kernel(const float* __restrict__ Sr, const float* __restrict__ Sf,
                             float* __restrict__ inv_nr, float* __restrict__ inv_nf,
                             int* __restrict__ opi, int* __restrict__ opj) {
    int p = blockIdx.x;
    int i = (int)((1.0f + sqrtf(8.0f * (float)p + 1.0f)) * 0.5f);
    while (i * (i - 1) / 2 > p) --i;
    while ((i + 1) * i / 2 <= p) ++i;
    int j = p - i * (i - 1) / 2;

    const float4* ri = (const float4*)(Sr + (size_t)i * D_);
    const float4* rj = (const float4*)(Sr + (size_t)j * D_);
    const float4* fi = (const float4*)(Sf + (size_t)i * D_);
    const float4* fj = (const float4*)(Sf + (size_t)j * D_);

    float sr = 0.f, sf = 0.f;
    for (int d = threadIdx.x; d < D_ / 4; d += 256) {
        float4 a = ri[d], b = rj[d];
        float dx = a.x - b.x, dy = a.y - b.y, dz = a.z - b.z, dw = a.w - b.w;
        sr += dx * dx + dy * dy + dz * dz + dw * dw;
        float4 c2 = fi[d], e = fj[d];
        dx = c2.x - e.x; dy = c2.y - e.y; dz = c2.z - e.z; dw = c2.w - e.w;
        sf += dx * dx + dy * dy + dz * dz + dw * dw;
    }
    #pragma unroll
    for (int off = 32; off > 0; off >>= 1) {
        sr += __shfl_down(sr, off, 64);
        sf += __shfl_down(sf, off, 64);
    }
    __shared__ float wr[4], wf[4];
    int wave = threadIdx.x >> 6;
    if ((threadIdx.x & 63) == 0) { wr[wave] = sr; wf[wave] = sf; }
    __syncthreads();
    if (threadIdx.x == 0) {
        inv_nr[p] = 1.0f / sqrtf(wr[0] + wr[1] + wr[2] + wr[3]);
        inv_nf[p] = 1.0f / sqrtf(wf[0] + wf[1] + wf[2] + wf[3]);
        opi[p] = i * D_;
        opj[p] = j * D_;
    }
}

__global__ void __launch_bounds__(256, 6)
tile3_kernel(const float* __restrict__ Sr, const float* __restrict__ Sf,
             const float* __restrict__ inv_nr, const float* __restrict__ inv_nf,
             const int* __restrict__ opi, const int* __restrict__ opj,
             float* __restrict__ partials) {
    __shared__ float Rt[64][65];
    __shared__ int   sIp[64], sJp[64];
    __shared__ float sInvF[64];
    __shared__ float wsum[4];

    int t  = threadIdx.x;
    int p0 = blockIdx.x * 64, q0 = blockIdx.y * 64;

    if (t < 64) {
        int p = p0 + t;
        sIp[t]   = opi[p];
        sJp[t]   = opj[p];
        sInvF[t] = inv_nf[p];
    }
    {
        int c  = t & 15;
        int qr = t >> 4;
        #pragma unroll
        for (int pass = 0; pass < 4; ++pass) {
            int qq = qr + 16 * pass;
            int q  = q0 + qq;
            int oi = opi[q], oj = opj[q];
            float invr = inv_nr[q];
            const float4 a = *(const float4*)(Sr + oi + p0 + 4 * c);
            const float4 b = *(const float4*)(Sr + oj + p0 + 4 * c);
            Rt[4 * c + 0][qq] = fmaxf((a.x - b.x) * invr, EPSV);
            Rt[4 * c + 1][qq] = fmaxf((a.y - b.y) * invr, EPSV);
            Rt[4 * c + 2][qq] = fmaxf((a.z - b.z) * invr, EPSV);
            Rt[4 * c + 3][qq] = fmaxf((a.w - b.w) * invr, EPSV);
        }
    }
    __syncthreads();

    int qg = t & 15;
    int pg = t >> 4;
    float ax = 0.f, ay = 0.f, az = 0.f, aw = 0.f;
    #pragma unroll
    for (int pp = 0; pp < 4; ++pp) {
        int prow = pg + 16 * pp;
        int oi = sIp[prow], oj = sJp[prow];
        float invf = sInvF[prow];
        const float4 fa = *(const float4*)(Sf + oi + q0 + 4 * qg);
        const float4 fb = *(const float4*)(Sf + oj + q0 + 4 * qg);
        const float4 r  = *(const float4*)&Rt[prow][4 * qg];
        ax += fmaxf((fa.x - fb.x) * invf, EPSV) * r.x;
        ay += fmaxf((fa.y - fb.y) * invf, EPSV) * r.y;
        az += fmaxf((fa.z - fb.z) * invf, EPSV) * r.z;
        aw += fmaxf((fa.w - fb.w) * invf, EPSV) * r.w;
    }
    float acc = (ax + ay) + (az + aw);

    #pragma unroll
    for (int off = 32; off > 0; off >>= 1) acc += __shfl_down(acc, off, 64);
    int w = t >> 6;
    if ((t & 63) == 0) wsum[w] = acc;
    __syncthreads();
    if (t == 0) partials[blockIdx.y * NT + blockIdx.x] = wsum[0] + wsum[1] + wsum[2] + wsum[3];
}

// ============ K5: final deterministic reduce (1024 thr) ============
__global__ void reduce_kernel(const float* __restrict__ partials, int n, float* __restrict__ out) {
    float s = 0.f;
    for (int idx = threadIdx.x; idx < n; idx += 1024) s += partials[idx];
    #pragma unroll
    for (int off = 32; off > 0; off >>= 1) s += __shfl_down(s, off, 64);
    __shared__ float wbuf[16];
    int wave = threadIdx.x >> 6;
    if ((threadIdx.x & 63) == 0) wbuf[wave] = s;
    __syncthreads();
    if (threadIdx.x == 0) {
        float tot = 0.f;
        #pragma unroll
        for (int k = 0; k < 16; ++k) tot += wbuf[k];
        out[0] = tot;
    }
}

extern "C" void kernel_launch(void* const* d_in, const int* in_sizes, int n_in,
                              void* d_out, int out_size, void* d_ws, size_t ws_size,
                              hipStream_t stream) {
    const float* Sr = (const float*)d_in[0];
    const float* Sf = (const float*)d_in[1];
    float* out = (float*)d_out;

    // ws layout (all sub-buffer sizes multiples of 16 B)
    char* w = (char*)d_ws;
    unsigned short* Sr16 = (unsigned short*)w;   w += (size_t)NS * DP_ * 2;            // 2.10 MB
    unsigned short* Sf16 = (unsigned short*)w;   w += (size_t)NS * DP_ * 2;            // 2.10 MB
    float* inv_nr = (float*)w;                   w += (size_t)PP * 4;
    float* inv_nf = (float*)w;                   w += (size_t)PP * 4;
    int*   opi    = (int*)w;                     w += (size_t)PP * 4;
    int*   opj    = (int*)w;                     w += (size_t)PP * 4;
    float* tpart  = (float*)w;                   w += (size_t)16384 * 4;               // >= max grid
    float* Gpart8 = (float*)w;                   w += (size_t)KS8 * 2 * NS * NS * 4;   // 1.05 MB
    size_t need = (size_t)(w - (char*)d_ws);

    if (ws_size >= need) {
        cvt_pad<<<1024, 256, 0, stream>>>(Sr, Sf, Sr16, Sf16);
        dim3 gg(64, 2, KS8);
        gram_direct<<<gg, 64, 0, stream>>>(Sr16, Sf16, Gpart8);
        norm_finish<<<32, 256, 0, stream>>>(Gpart8, inv_nr, inv_nf, opi, opj);
        dim3 grid(16, 128);
        tile13_kernel<<<grid, 256, 0, stream>>>(Sr16, Sf16, inv_nr, inv_nf, opi, opj, tpart);
        reduce_kernel<<<1, 1024, 0, stream>>>(tpart, 2048, out);
    } else {
        norms_kernel<<<P_, 256, 0, stream>>>(Sr, Sf, inv_nr, inv_nf, opi, opj);
        dim3 grid(NT, NT);
        tile3_kernel<<<grid, 256, 0, stream>>>(Sr, Sf, inv_nr, inv_nf, opi, opj, tpart);
        reduce_kernel<<<1, 1024, 0, stream>>>(tpart, NT * NT, out);
    }
}